// Round 1
// baseline (915.350 us; speedup 1.0000x reference)
//
#include <hip/hip_runtime.h>

static constexpr int THREADS = 256;

// ---------------------------------------------------------------------------
// Kernel 1: zero the scatter targets + accumulators + output.
// ---------------------------------------------------------------------------
__global__ __launch_bounds__(THREADS) void kkt_zero(
    float* __restrict__ Ax, float* __restrict__ ATlam,
    double* __restrict__ acc, float* __restrict__ out,
    int sum_m, int sum_n) {
  int idx = blockIdx.x * blockDim.x + threadIdx.x;
  int stride = gridDim.x * blockDim.x;
  int total = sum_m + sum_n;
  for (int i = idx; i < total; i += stride) {
    if (i < sum_m) Ax[i] = 0.0f;
    else           ATlam[i - sum_m] = 0.0f;
  }
  if (idx < 4) acc[idx] = 0.0;
  if (idx == 0) out[0] = 0.0f;
}

// ---------------------------------------------------------------------------
// Kernel 2: fused edge pass. One read of (row, col, attr) per edge, both
// scatter-adds done here. int4/float4 loads = 16B/lane coalesced.
// unsafeAtomicAdd -> hardware global_atomic_add_f32 (no CAS loop).
// ---------------------------------------------------------------------------
__global__ __launch_bounds__(THREADS) void kkt_edges(
    const int* __restrict__ rows, const int* __restrict__ cols,
    const float* __restrict__ attr,
    const float* __restrict__ x, const float* __restrict__ lam,
    float* __restrict__ Ax, float* __restrict__ ATlam, int E) {
  int idx = blockIdx.x * blockDim.x + threadIdx.x;
  int stride = gridDim.x * blockDim.x;
  int e4 = E >> 2;
  const int4*   rows4 = reinterpret_cast<const int4*>(rows);
  const int4*   cols4 = reinterpret_cast<const int4*>(cols);
  const float4* attr4 = reinterpret_cast<const float4*>(attr);
  for (int i = idx; i < e4; i += stride) {
    int4   r = rows4[i];
    int4   c = cols4[i];
    float4 a = attr4[i];
    // gathers first (L2-resident: x/lam are 512 KB each)
    float xc0 = x[c.x], xc1 = x[c.y], xc2 = x[c.z], xc3 = x[c.w];
    float lr0 = lam[r.x], lr1 = lam[r.y], lr2 = lam[r.z], lr3 = lam[r.w];
    unsafeAtomicAdd(&Ax[r.x], a.x * xc0);
    unsafeAtomicAdd(&Ax[r.y], a.y * xc1);
    unsafeAtomicAdd(&Ax[r.z], a.z * xc2);
    unsafeAtomicAdd(&Ax[r.w], a.w * xc3);
    unsafeAtomicAdd(&ATlam[c.x], a.x * lr0);
    unsafeAtomicAdd(&ATlam[c.y], a.y * lr1);
    unsafeAtomicAdd(&ATlam[c.z], a.z * lr2);
    unsafeAtomicAdd(&ATlam[c.w], a.w * lr3);
  }
  // scalar tail (E not divisible by 4)
  for (int i = (e4 << 2) + idx; i < E; i += stride) {
    int r = rows[i], c = cols[i];
    float a = attr[i];
    unsafeAtomicAdd(&Ax[r], a * x[c]);
    unsafeAtomicAdd(&ATlam[c], a * lam[r]);
  }
}

// ---------------------------------------------------------------------------
// Kernel 3: loss vectors + reduction. Uniform segment sizes mean
// seg_mean_sq(v).sum() == sum(v*v)/per, so we only need 4 global sums.
// fp64 accumulation (sum of 131K squares ~1e6-1e7; fp32 would lose ~1 digit).
// ---------------------------------------------------------------------------
__global__ __launch_bounds__(THREADS) void kkt_loss(
    const float* __restrict__ Ax, const float* __restrict__ ATlam,
    const float* __restrict__ bcat, const float* __restrict__ ccat,
    const float* __restrict__ lam, double* __restrict__ acc,
    int sum_m, int sum_n) {
  int idx = blockIdx.x * blockDim.x + threadIdx.x;
  int stride = gridDim.x * blockDim.x;
  double pr = 0.0, du = 0.0, st = 0.0, cs = 0.0;
  for (int i = idx; i < sum_m; i += stride) {
    float d  = Ax[i] - bcat[i];
    float li = lam[i];
    float p    = d > 0.0f ? d : 0.0f;
    float u    = li < 0.0f ? -li : 0.0f;
    float comp = li * d;
    pr += (double)p * p;
    du += (double)u * u;
    cs += (double)comp * comp;
  }
  for (int i = idx; i < sum_n; i += stride) {
    float s = ATlam[i] + ccat[i];
    st += (double)s * s;
  }
  // wave-64 butterfly reduce, then one fp64 atomic per wave per accumulator
  for (int off = 32; off > 0; off >>= 1) {
    pr += __shfl_down(pr, off);
    du += __shfl_down(du, off);
    st += __shfl_down(st, off);
    cs += __shfl_down(cs, off);
  }
  if ((threadIdx.x & 63) == 0) {
    unsafeAtomicAdd(&acc[0], pr);
    unsafeAtomicAdd(&acc[1], du);
    unsafeAtomicAdd(&acc[2], st);
    unsafeAtomicAdd(&acc[3], cs);
  }
}

// ---------------------------------------------------------------------------
// Kernel 4: weights + per-count scaling + /B. Scalars read from device.
// ---------------------------------------------------------------------------
__global__ void kkt_finalize(const double* __restrict__ acc,
                             const int* __restrict__ Bp,
                             const int* __restrict__ mp,
                             const int* __restrict__ np_,
                             float* __restrict__ out) {
  double m = (double)mp[0];
  double n = (double)np_[0];
  double B = (double)Bp[0];
  double total =
      (0.1 * (acc[0] + acc[1]) / m + 0.6 * acc[2] / n + 0.2 * acc[3] / m) / B;
  out[0] = (float)total;
}

extern "C" void kernel_launch(void* const* d_in, const int* in_sizes, int n_in,
                              void* d_out, int out_size, void* d_ws, size_t ws_size,
                              hipStream_t stream) {
  const float* x    = (const float*)d_in[0];
  const float* lam  = (const float*)d_in[1];
  const int*   rows = (const int*)d_in[2];
  const int*   cols = (const int*)d_in[3];
  const float* attr = (const float*)d_in[4];
  const float* bcat = (const float*)d_in[5];
  const float* ccat = (const float*)d_in[6];
  const int*   Bp   = (const int*)d_in[7];
  const int*   mp   = (const int*)d_in[8];
  const int*   np_  = (const int*)d_in[9];

  const int sum_n = in_sizes[0];
  const int sum_m = in_sizes[1];
  const int E     = in_sizes[2];

  char*   ws    = (char*)d_ws;
  double* acc   = (double*)ws;            // 4 doubles
  float*  Ax    = (float*)(ws + 64);      // [sum_m]
  float*  ATlam = Ax + sum_m;             // [sum_n]
  float*  out   = (float*)d_out;

  int zb = (sum_m + sum_n + THREADS - 1) / THREADS;
  if (zb > 2048) zb = 2048;
  kkt_zero<<<zb, THREADS, 0, stream>>>(Ax, ATlam, acc, out, sum_m, sum_n);

  int work = E / 4;
  int eb = (work + THREADS - 1) / THREADS;
  if (eb > 2048) eb = 2048;
  kkt_edges<<<eb, THREADS, 0, stream>>>(rows, cols, attr, x, lam, Ax, ATlam, E);

  int lw = sum_m > sum_n ? sum_m : sum_n;
  int lb = (lw + THREADS - 1) / THREADS;
  if (lb > 1024) lb = 1024;
  kkt_loss<<<lb, THREADS, 0, stream>>>(Ax, ATlam, bcat, ccat, lam, acc, sum_m, sum_n);

  kkt_finalize<<<1, 1, 0, stream>>>(acc, Bp, mp, np_, out);
}